// Round 2
// baseline (386.596 us; speedup 1.0000x reference)
//
#include <hip/hip_runtime.h>
#include <hip/hip_bf16.h>

typedef unsigned short u16;
typedef __bf16 bf16x8 __attribute__((ext_vector_type(8)));
typedef float f32x4 __attribute__((ext_vector_type(4)));

#define T_TOK 1024
#define HID   2048
#define IMM   768
#define NE    8
#define TWOI  1536

static __device__ __forceinline__ u16 f2bf(float f) {
  unsigned u = __float_as_uint(f);
  u += 0x7FFFu + ((u >> 16) & 1u);   // RNE
  return (u16)(u >> 16);
}
static __device__ __forceinline__ float bf2f(u16 s) {
  return __uint_as_float(((unsigned)s) << 16);
}

// ---------------- router: logits -> softmax -> top2 -> renorm -> slot lists
__global__ __launch_bounds__(64) void router_kernel(
    const float* __restrict__ hid, const float* __restrict__ gw,
    int* __restrict__ cnt, int* __restrict__ tok_of, float* __restrict__ wslot)
{
  const int t = blockIdx.x;
  const int lane = threadIdx.x;
  float acc[NE];
#pragma unroll
  for (int e = 0; e < NE; ++e) acc[e] = 0.f;
  const float4* h4 = (const float4*)(hid + (long)t * HID);
#pragma unroll 2
  for (int c = lane; c < HID / 4; c += 64) {
    float4 x = h4[c];
#pragma unroll
    for (int e = 0; e < NE; ++e) {
      float4 w = ((const float4*)(gw + e * HID))[c];
      acc[e] += x.x * w.x + x.y * w.y + x.z * w.z + x.w * w.w;
    }
  }
#pragma unroll
  for (int e = 0; e < NE; ++e) {
    float v = acc[e];
#pragma unroll
    for (int off = 32; off > 0; off >>= 1) v += __shfl_xor(v, off, 64);
    acc[e] = v;
  }
  if (lane == 0) {
    float mx = acc[0];
#pragma unroll
    for (int e = 1; e < NE; ++e) mx = fmaxf(mx, acc[e]);
    float p[NE]; float s = 0.f;
#pragma unroll
    for (int e = 0; e < NE; ++e) { p[e] = expf(acc[e] - mx); s += p[e]; }
    const float inv = 1.f / s;
    float p1 = -1.f, p2 = -1.f; int i1 = 0, i2 = 0;
#pragma unroll
    for (int e = 0; e < NE; ++e) {
      float pe = p[e] * inv;
      if (pe > p1)      { p2 = p1; i2 = i1; p1 = pe; i1 = e; }
      else if (pe > p2) { p2 = pe; i2 = e; }
    }
    const float wsum = p1 + p2;
    int s1 = atomicAdd(&cnt[i1], 1);
    tok_of[i1 * T_TOK + s1] = t;
    wslot[i1 * T_TOK + s1] = p1 / wsum;
    int s2 = atomicAdd(&cnt[i2], 1);
    tok_of[i2 * T_TOK + s2] = t;
    wslot[i2 * T_TOK + s2] = p2 / wsum;
  }
}

// ---------------- hidden fp32 -> bf16
__global__ __launch_bounds__(256) void cvt_kernel(
    const float* __restrict__ in, u16* __restrict__ out)
{
  const int i = blockIdx.x * 256 + threadIdx.x;   // grid sized exactly: T*H/4 threads
  float4 x = ((const float4*)in)[i];
  ushort4 o;
  o.x = f2bf(x.x); o.y = f2bf(x.y); o.z = f2bf(x.z); o.w = f2bf(x.w);
  ((ushort4*)out)[i] = o;
}

// ---------------- grouped B^T GEMM over expert slot-space.
// C[slot,n] = sum_k A[row(slot),k]*B[n,k] for slots < cnt[z] (block-granular
// early exit; fixed capacity grid for graph capture).
// GATHER_A: A row = tok_of[z*T+slot] (GEMM1, A=hidden bf16). else A is slot-space.
// OUT_ATOMIC: scatter-atomicAdd into Cf[tok_of[slot]] masked to slot<cnt (GEMM2).
//             else plain bf16 store to slot-space Cb (GEMM1, garbage rows ok).
template<int K, bool GATHER_A, bool OUT_ATOMIC>
__global__ __launch_bounds__(256, 2) void gemm_moe(
    const u16* __restrict__ A, int lda, long a_zoff,
    const float* __restrict__ B, long b_zoff,
    const int* __restrict__ tok_of, const int* __restrict__ cnt,
    u16* __restrict__ Cb, float* __restrict__ Cf, int ldc, long c_zoff)
{
  constexpr int BM = 128, BN = 128, BK = 32;
  constexpr int LSTR = BK + 8;        // +16B pad: breaks 64B-stride bank pattern
  constexpr int NKT = K / BK;
  static_assert(NKT >= 2 && (K % BK) == 0, "K must be multiple of 32, >=64");

  const int z = blockIdx.z;
  const int nrow = cnt[z];
  const long m0 = (long)blockIdx.x * BM;
  if (m0 >= nrow) return;              // uniform per block

  __shared__ __align__(16) u16 As[2][BM * LSTR];
  __shared__ __align__(16) u16 Bs[2][BN * LSTR];

  const int tid  = threadIdx.x;
  const int lane = tid & 63;
  const int wave = tid >> 6;
  const int wm = wave >> 1, wn = wave & 1;   // 2x2 waves, each 64x64 out
  const int lrow = lane & 15;
  const int lk   = (lane >> 4) << 3;         // 8 contiguous k per lane

  const long n0 = (long)blockIdx.y * BN;
  const float* Bb = B + b_zoff * z + n0 * (long)K;

  // staging: thread owns A slots m0+r0, m0+r0+64 and B rows n0+r0, n0+r0+64
  const int r0  = tid >> 2;
  const int cs0 = (tid & 3) << 3;

  const u16 *ap0, *ap1;
  if constexpr (GATHER_A) {
    ap0 = A + (long)tok_of[z * T_TOK + m0 + r0] * lda + cs0;
    ap1 = A + (long)tok_of[z * T_TOK + m0 + r0 + 64] * lda + cs0;
  } else {
    ap0 = A + a_zoff * z + (m0 + r0) * (long)lda + cs0;
    ap1 = ap0 + 64l * lda;
  }

  uint4 sa0, sa1; float4 sb0a, sb0b, sb1a, sb1b;

  auto gload = [&](int kk) {
    sa0 = *(const uint4*)(ap0 + kk);
    sa1 = *(const uint4*)(ap1 + kk);
    const float* bp = Bb + (long)r0 * K + kk + cs0;
    sb0a = *(const float4*)bp;
    sb0b = *(const float4*)(bp + 4);
    sb1a = *(const float4*)(bp + 64l * K);
    sb1b = *(const float4*)(bp + 64l * K + 4);
  };
  auto packb = [&](const float4& f0, const float4& f1) -> uint4 {
    return make_uint4(
      (unsigned)f2bf(f0.x) | ((unsigned)f2bf(f0.y) << 16),
      (unsigned)f2bf(f0.z) | ((unsigned)f2bf(f0.w) << 16),
      (unsigned)f2bf(f1.x) | ((unsigned)f2bf(f1.y) << 16),
      (unsigned)f2bf(f1.z) | ((unsigned)f2bf(f1.w) << 16));
  };
  auto swrite = [&](int buf) {
    *(uint4*)&As[buf][r0 * LSTR + cs0]        = sa0;
    *(uint4*)&As[buf][(r0 + 64) * LSTR + cs0] = sa1;
    *(uint4*)&Bs[buf][r0 * LSTR + cs0]        = packb(sb0a, sb0b);
    *(uint4*)&Bs[buf][(r0 + 64) * LSTR + cs0] = packb(sb1a, sb1b);
  };

  f32x4 acc[4][4];
  const f32x4 zero4 = {0.f, 0.f, 0.f, 0.f};
#pragma unroll
  for (int m = 0; m < 4; ++m)
#pragma unroll
    for (int n = 0; n < 4; ++n) acc[m][n] = zero4;

  auto compute = [&](int buf) {
    bf16x8 af[4], bfr[4];
#pragma unroll
    for (int m = 0; m < 4; ++m)
      af[m] = *(const bf16x8*)&As[buf][(wm * 64 + m * 16 + lrow) * LSTR + lk];
#pragma unroll
    for (int n = 0; n < 4; ++n)
      bfr[n] = *(const bf16x8*)&Bs[buf][(wn * 64 + n * 16 + lrow) * LSTR + lk];
#pragma unroll
    for (int m = 0; m < 4; ++m)
#pragma unroll
      for (int n = 0; n < 4; ++n)
        acc[m][n] = __builtin_amdgcn_mfma_f32_16x16x32_bf16(af[m], bfr[n], acc[m][n], 0, 0, 0);
  };

  gload(0);
  swrite(0);
  __syncthreads();
  int cur = 0;
#pragma unroll 1
  for (int kt = 0; kt < NKT - 1; ++kt) {
    gload((kt + 1) * BK);    // issue next tile's global loads (hide under MFMA)
    compute(cur);
    swrite(cur ^ 1);
    __syncthreads();
    cur ^= 1;
  }
  compute(cur);

  // epilogue: per 16x16 frag, col = lane&15, row = (lane>>4)*4 + j   [m89-verified]
  const int rloc = wm * 64 + ((lane >> 4) << 2);
  const long cbase = n0 + wn * 64 + lrow;
#pragma unroll
  for (int m = 0; m < 4; ++m) {
#pragma unroll
    for (int n = 0; n < 4; ++n) {
#pragma unroll
      for (int j = 0; j < 4; ++j) {
        const long slot = m0 + rloc + m * 16 + j;
        const long col = cbase + n * 16;
        if constexpr (OUT_ATOMIC) {
          if (slot < nrow) {
            const long tok = tok_of[z * T_TOK + slot];
            atomicAdd(Cf + tok * ldc + col, acc[m][n][j]);
          }
        } else {
          Cb[c_zoff * z + slot * ldc + col] = f2bf(acc[m][n][j]);
        }
      }
    }
  }
}

// ---------------- slot-space: hp[g,i] = wslot[g] * silu(g_) * u_
__global__ __launch_bounds__(256) void silu_kernel(
    const u16* __restrict__ gu, const float* __restrict__ wslot,
    u16* __restrict__ hp)
{
  const int c = blockIdx.x * 256 + threadIdx.x;   // grid: E*T*IMM/8 threads
  const int idx = c << 3;
  const int g = idx / IMM;            // global slot 0..E*T-1
  const int i0 = idx - g * IMM;
  const u16* gp = gu + (long)g * TWOI + i0;
  uint4 gv = *(const uint4*)gp;
  uint4 uv = *(const uint4*)(gp + IMM);
  const float cw = wslot[g];
  const unsigned* gwv = (const unsigned*)&gv;
  const unsigned* uwv = (const unsigned*)&uv;
  unsigned outw[4];
#pragma unroll
  for (int q = 0; q < 4; ++q) {
    float g0 = bf2f((u16)(gwv[q] & 0xFFFFu));
    float g1 = bf2f((u16)(gwv[q] >> 16));
    float u0 = bf2f((u16)(uwv[q] & 0xFFFFu));
    float u1 = bf2f((u16)(uwv[q] >> 16));
    float h0 = cw * u0 * (g0 / (1.f + __expf(-g0)));
    float h1 = cw * u1 * (g1 / (1.f + __expf(-g1)));
    outw[q] = (unsigned)f2bf(h0) | ((unsigned)f2bf(h1) << 16);
  }
  *(uint4*)(hp + (long)g * IMM + i0) = make_uint4(outw[0], outw[1], outw[2], outw[3]);
}

extern "C" void kernel_launch(void* const* d_in, const int* in_sizes, int n_in,
                              void* d_out, int out_size, void* d_ws, size_t ws_size,
                              hipStream_t stream) {
  const float* hid = (const float*)d_in[0];   // [T, H]
  const float* gw  = (const float*)d_in[1];   // [E, H]
  const float* wgu = (const float*)d_in[2];   // [E, 2I, H]
  const float* wd  = (const float*)d_in[3];   // [E, H, I]
  float* out = (float*)d_out;                 // [T, H] fp32

  // ws layout (~40.2 MiB):
  char* ws = (char*)d_ws;
  u16*   hidb   = (u16*)ws;                                   // 4 MiB   [T][H] bf16
  int*   cnt    = (int*)(ws + (4l << 20));                    // 32 B (padded to 4 KiB)
  int*   tok_of = (int*)(ws + (4l << 20) + (1l << 12));       // 32 KiB  [E][T]
  float* wslot  = (float*)(ws + (4l << 20) + (1l << 12) + (1l << 15)); // 32 KiB [E][T]
  u16*   gu     = (u16*)(ws + (4l << 20) + (1l << 17));       // 24 MiB  [E][T][2I] bf16
  u16*   hp     = (u16*)(ws + (4l << 20) + (1l << 17)
                            + (long)NE * T_TOK * TWOI * 2);   // 12 MiB  [E][T][IMM] bf16

  // zero: out (atomic target), cnt/tok_of/wslot (router fills; zero default
  // makes padded slots read token 0 / weight 0 -> no OOB, no NaN)
  hipMemsetAsync(d_out, 0, (size_t)out_size * sizeof(float), stream);
  hipMemsetAsync(ws + (4l << 20), 0, (1l << 17), stream);

  router_kernel<<<T_TOK, 64, 0, stream>>>(hid, gw, cnt, tok_of, wslot);
  cvt_kernel<<<(T_TOK * HID / 4) / 256, 256, 0, stream>>>(hid, hidb);
  // GEMM1 (gathered): gu[e][slot] = hidden[tok] @ wgu[e]^T   (N=1536, K=2048)
  gemm_moe<HID, true, false><<<dim3(T_TOK / 128, TWOI / 128, NE), 256, 0, stream>>>(
      hidb, HID, 0, wgu, (long)TWOI * HID,
      tok_of, cnt, gu, nullptr, TWOI, (long)T_TOK * TWOI);
  silu_kernel<<<(NE * T_TOK * IMM / 8) / 256, 256, 0, stream>>>(gu, wslot, hp);
  // GEMM2 (scatter-atomic): out[tok] += hp[e][slot] @ wd[e]^T  (N=2048, K=768)
  gemm_moe<IMM, false, true><<<dim3(T_TOK / 128, HID / 128, NE), 256, 0, stream>>>(
      hp, IMM, (long)T_TOK * IMM, wd, (long)HID * IMM,
      tok_of, cnt, nullptr, out, HID, 0);
}